// Round 5
// baseline (247.512 us; speedup 1.0000x reference)
//
#include <hip/hip_runtime.h>
#include <math.h>

#define D_MODEL 2048
#define NE 8
#define TOKENS 16384

// output layout (floats): probs[16384*8], idx[16384*2], topp[16384*2], aux[1]
#define OUT_IDX   131072
#define OUT_TOPP  163840
#define OUT_AUX   196608

// ws layout (bytes)
#define WS_SPR    0        // double[1]  (zeroed)
#define WS_CNT    8        // uint[1]    (zeroed)
#define WS_GP     16       // float[8]   (zeroed)
#define WS_GC     48       // float[8]   (zeroed)
#define WS_SIMP   1024     // float[KS][65536], fully written by spr_gemm

// ---------------------------------------------------------------------------
// Router: 1024 blocks x 512 threads (8 waves), W staged once in 64KB LDS.
// Each wave computes 2 tokens with the `it` loop OUTER: the 8 W fragments are
// read from LDS and converted to f64 ONCE per iteration, then FMA'd into both
// tokens' accumulators (halves LDS traffic + W cvts vs token-outer).
// f64 logits end-to-end (top-k tie safety); log-fold shuffle reduction.
// ---------------------------------------------------------------------------
__global__ __launch_bounds__(512, 4) void router_k(
    const float* __restrict__ x, const float* __restrict__ W,
    float* __restrict__ out, float* __restrict__ gP, float* __restrict__ gC)
{
    __shared__ float4 Wl[NE * 512];   // 64 KB
    __shared__ float Pl[NE], Cl[NE];
    const int tid = threadIdx.x;
    {
        const float4* W4 = (const float4*)W;
#pragma unroll
        for (int i = 0; i < 8; ++i) Wl[tid + i * 512] = W4[tid + i * 512];
    }
    if (tid < NE) { Pl[tid] = 0.f; Cl[tid] = 0.f; }
    __syncthreads();

    const int wave = tid >> 6, lane = tid & 63;
    const int keep5 = (lane >> 5) & 1, keep4 = (lane >> 4) & 1, keep3 = (lane >> 3) & 1;
    const int emine = keep3 + 2 * keep4 + 4 * keep5;  // expert owned after folding
    const int t0 = blockIdx.x * 16 + wave * 2;        // this wave's 2 tokens

    const float4* xp0 = (const float4*)(x + (size_t)t0 * D_MODEL);
    const float4* xp1 = (const float4*)(x + (size_t)(t0 + 1) * D_MODEL);

    double acc0[NE] = {0, 0, 0, 0, 0, 0, 0, 0};
    double acc1[NE] = {0, 0, 0, 0, 0, 0, 0, 0};

#pragma unroll 2
    for (int it = 0; it < 8; ++it) {
        const float4 xa = xp0[it * 64 + lane];
        const float4 xb = xp1[it * 64 + lane];
        const double a0 = xa.x, a1 = xa.y, a2 = xa.z, a3 = xa.w;
        const double b0 = xb.x, b1 = xb.y, b2 = xb.z, b3 = xb.w;
#pragma unroll
        for (int e = 0; e < NE; ++e) {
            const float4 wv = Wl[e * 512 + it * 64 + lane];
            const double w0 = wv.x, w1 = wv.y, w2 = wv.z, w3 = wv.w;  // cvt once, used twice
            acc0[e] += a0 * w0 + a1 * w1 + a2 * w2 + a3 * w3;
            acc1[e] += b0 * w0 + b1 * w1 + b2 * w2 + b3 * w3;
        }
    }

#pragma unroll 1
    for (int tt = 0; tt < 2; ++tt) {
        const int t = t0 + tt;
        double a[NE];
#pragma unroll
        for (int e = 0; e < NE; ++e) a[e] = tt ? acc1[e] : acc0[e];

        // ---- log-fold reduce: experts fold into lane groups ----
#pragma unroll
        for (int j = 0; j < 4; ++j) {           // xor 32
            double keep = keep5 ? a[j + 4] : a[j];
            double send = keep5 ? a[j] : a[j + 4];
            a[j] = keep + __shfl_xor(send, 32, 64);
        }
#pragma unroll
        for (int j = 0; j < 2; ++j) {           // xor 16
            double keep = keep4 ? a[j + 2] : a[j];
            double send = keep4 ? a[j] : a[j + 2];
            a[j] = keep + __shfl_xor(send, 16, 64);
        }
        {                                        // xor 8
            double keep = keep3 ? a[1] : a[0];
            double send = keep3 ? a[0] : a[1];
            a[0] = keep + __shfl_xor(send, 8, 64);
        }
        double L = a[0];
        L += __shfl_xor(L, 4, 64);
        L += __shfl_xor(L, 2, 64);
        L += __shfl_xor(L, 1, 64);
        // L = logit[emine]; identical across the 8 lanes of each group.

        // top-1 across groups (lowest index wins ties = jax.lax.top_k)
        double v1 = L; int i1 = emine;
#pragma unroll
        for (int off = 8; off <= 32; off <<= 1) {
            double ov = __shfl_xor(v1, off, 64);
            int oi = __shfl_xor(i1, off, 64);
            if (ov > v1 || (ov == v1 && oi < i1)) { v1 = ov; i1 = oi; }
        }
        // top-2
        double v2 = (emine == i1) ? -1e300 : L;
        int i2 = (emine == i1) ? NE : emine;
#pragma unroll
        for (int off = 8; off <= 32; off <<= 1) {
            double ov = __shfl_xor(v2, off, 64);
            int oi = __shfl_xor(i2, off, 64);
            if (ov > v2 || (ov == v2 && oi < i2)) { v2 = ov; i2 = oi; }
        }
        // softmax (f32; output tolerance is loose)
        float p = __expf((float)(L - v1));
        float s = p;
#pragma unroll
        for (int off = 8; off <= 32; off <<= 1) s += __shfl_xor(s, off, 64);
        const float pr = p / s;

        if ((lane & 7) == 0) {
            out[(size_t)t * NE + emine] = pr;
            atomicAdd(&Pl[emine], pr);
        }
        if (lane == 0) {
            out[OUT_IDX + t * 2]     = (float)i1;
            out[OUT_IDX + t * 2 + 1] = (float)i2;
            const float e2 = __expf((float)(v2 - v1));   // pr2/pr1
            out[OUT_TOPP + t * 2]     = 1.0f / (1.0f + e2);
            out[OUT_TOPP + t * 2 + 1] = e2 / (1.0f + e2);
            atomicAdd(&Cl[i1], 1.f);
            atomicAdd(&Cl[i2], 1.f);
        }
    }
    __syncthreads();
    if (tid < NE) { atomicAdd(&gP[tid], Pl[tid]); atomicAdd(&gC[tid], Cl[tid]); }
}

// ---------------------------------------------------------------------------
// SPR raw-dot GEMM, grid (4,4,KS), 256 thr, 64x64 tile, 4x4 reg blocking.
// Each bk writes its own partial buffer (no atomics). nkc = 32/KS.
// ---------------------------------------------------------------------------
__global__ __launch_bounds__(256) void spr_gemm(
    const float* __restrict__ x, const int* __restrict__ spr_idx,
    float* __restrict__ simP, int nkc)
{
    __shared__ float A[64][65];
    __shared__ float B[64][65];
    __shared__ int ra[64], rb[64];
    const int bi = blockIdx.x, bj = blockIdx.y, bk = blockIdx.z;
    const int tid = threadIdx.x;
    if (tid < 64) ra[tid] = spr_idx[bi * 64 + tid];
    else if (tid < 128) rb[tid - 64] = spr_idx[bj * 64 + (tid - 64)];
    __syncthreads();

    const int tx = tid & 15, ty = tid >> 4;
    float acc[4][4] = {};

    for (int kc = 0; kc < nkc; ++kc) {
        const int k0 = (bk * nkc + kc) * 64;
#pragma unroll
        for (int l = 0; l < 4; ++l) {
            const int lin = l * 256 + tid;
            const int r = lin >> 4, c4 = lin & 15;
            float4 v = *(const float4*)(x + (size_t)ra[r] * D_MODEL + k0 + c4 * 4);
            A[r][c4 * 4] = v.x; A[r][c4 * 4 + 1] = v.y; A[r][c4 * 4 + 2] = v.z; A[r][c4 * 4 + 3] = v.w;
            float4 w = *(const float4*)(x + (size_t)rb[r] * D_MODEL + k0 + c4 * 4);
            B[r][c4 * 4] = w.x; B[r][c4 * 4 + 1] = w.y; B[r][c4 * 4 + 2] = w.z; B[r][c4 * 4 + 3] = w.w;
        }
        __syncthreads();
#pragma unroll 4
        for (int k = 0; k < 64; ++k) {
            float a[4], b[4];
#pragma unroll
            for (int u = 0; u < 4; ++u) { a[u] = A[ty * 4 + u][k]; b[u] = B[tx * 4 + u][k]; }
#pragma unroll
            for (int u = 0; u < 4; ++u)
#pragma unroll
                for (int v = 0; v < 4; ++v) acc[u][v] += a[u] * b[v];
        }
        __syncthreads();
    }
    float* dst = simP + (size_t)bk * 65536;
#pragma unroll
    for (int u = 0; u < 4; ++u)
#pragma unroll
        for (int v = 0; v < 4; ++v)
            dst[(bi * 64 + ty * 4 + u) * 256 + (bj * 64 + tx * 4 + v)] = acc[u][v];
}

// ---------------------------------------------------------------------------
// SPR loss (norms from sim diagonal, router norms from probs) + last-block
// aux-loss finalize. 256 blocks (row i) x 256 threads (col j).
// ---------------------------------------------------------------------------
__global__ __launch_bounds__(256) void spr_finish(
    const float* __restrict__ simP, const int* __restrict__ spr_idx,
    const float* __restrict__ out_probs, const float* __restrict__ gP,
    const float* __restrict__ gC, double* __restrict__ spr_sum,
    unsigned* __restrict__ counter, float* __restrict__ out, int ks)
{
    const int i = blockIdx.x, j = threadIdx.x;
    __shared__ float rni[NE];
    __shared__ double red[4];

    float raw = 0.f, dj = 0.f;
    for (int s = 0; s < ks; ++s) raw += simP[(size_t)s * 65536 + i * 256 + j];
    for (int s = 0; s < ks; ++s) dj  += simP[(size_t)s * 65536 + j * 257];

    const int rowj = spr_idx[j];
    const float4* pp = (const float4*)(out_probs + (size_t)rowj * NE);
    float4 pv0 = pp[0], pv1 = pp[1];
    float rs = pv0.x * pv0.x + pv0.y * pv0.y + pv0.z * pv0.z + pv0.w * pv0.w +
               pv1.x * pv1.x + pv1.y * pv1.y + pv1.z * pv1.z + pv1.w * pv1.w;
    const float rinv = 1.0f / fmaxf(sqrtf(rs), 1e-12f);
    float rnj[NE] = { pv0.x * rinv, pv0.y * rinv, pv0.z * rinv, pv0.w * rinv,
                      pv1.x * rinv, pv1.y * rinv, pv1.z * rinv, pv1.w * rinv };
    if (j == i) {
#pragma unroll
        for (int e = 0; e < NE; ++e) rni[e] = rnj[e];
        red[3] = (double)dj;
    }
    __syncthreads();
    const float di = (float)red[3];
    float rsim = 0.f;
#pragma unroll
    for (int e = 0; e < NE; ++e) rsim += rni[e] * rnj[e];
    const float ni = fmaxf(sqrtf(di), 1e-12f), nj = fmaxf(sqrtf(dj), 1e-12f);
    const float isim = raw / (ni * nj);
    const double d = (double)rsim - (double)isim;
    double sq = d * d;
#pragma unroll
    for (int off = 32; off; off >>= 1) sq += __shfl_xor(sq, off, 64);
    __syncthreads();
    const int wave = j >> 6, lane = j & 63;
    if (lane == 0) red[wave] = sq;
    __syncthreads();
    if (j == 0) {
        atomicAdd(spr_sum, red[0] + red[1] + red[2] + red[3]);
        __threadfence();
        const unsigned old = atomicAdd(counter, 1u);
        if (old == 255u) {
            const double spr = atomicAdd(spr_sum, 0.0) / 65536.0;
            double lb = 0.0, dpsl = 0.0;
            for (int e = 0; e < NE; ++e) {
                const double Pi = (double)gP[e] / (double)TOKENS;
                const double fi = (double)gC[e] / (double)(TOKENS * 2);
                lb += fi * Pi;
                dpsl += 0.125 * (log(0.125) - log(Pi));
            }
            lb *= 8.0;
            out[OUT_AUX] = (float)(0.01 * (lb + dpsl + 0.1 * spr));
        }
    }
}

extern "C" void kernel_launch(void* const* d_in, const int* in_sizes, int n_in,
                              void* d_out, int out_size, void* d_ws, size_t ws_size,
                              hipStream_t stream)
{
    const float* x = (const float*)d_in[0];
    const float* W = (const float*)d_in[1];
    const int* spr_idx = (const int*)d_in[2];
    float* out = (float*)d_out;
    char* ws = (char*)d_ws;

    double*   spr_sum = (double*)(ws + WS_SPR);
    unsigned* counter = (unsigned*)(ws + WS_CNT);
    float*    gP      = (float*)(ws + WS_GP);
    float*    gC      = (float*)(ws + WS_GC);
    float*    simP    = (float*)(ws + WS_SIMP);

    // pick largest K-split whose partial buffers fit the workspace
    int ks = 8;
    if (ws_size >= (size_t)WS_SIMP + 32u * 65536u * 4u) ks = 32;
    else if (ws_size >= (size_t)WS_SIMP + 16u * 65536u * 4u) ks = 16;
    const int nkc = 32 / ks;

    hipMemsetAsync(ws, 0, 128, stream);   // spr_sum + counter + gP + gC

    router_k<<<TOKENS / 16, 512, 0, stream>>>(x, W, out, gP, gC);
    spr_gemm<<<dim3(4, 4, ks), 256, 0, stream>>>(x, spr_idx, simP, nkc);
    spr_finish<<<256, 256, 0, stream>>>(simP, spr_idx, out, gP, gC, spr_sum, counter, out, ks);
}

// Round 6
// 246.851 us; speedup vs baseline: 1.0027x; 1.0027x over previous
//
#include <hip/hip_runtime.h>
#include <math.h>

#define D_MODEL 2048
#define NE 8
#define TOKENS 16384
#define RBLK 512           // router blocks (32 tokens each)

// output layout (floats): probs[16384*8], idx[16384*2], topp[16384*2], aux[1]
#define OUT_IDX   131072
#define OUT_TOPP  163840
#define OUT_AUX   196608

// ws layout (bytes)
#define WS_SPR    0        // double[1]  (zeroed by memset)
#define WS_CNT    8        // uint[1]    (zeroed by memset)
#define WS_BP     64       // float[512*8]  router per-block P-sums (plain stores)
#define WS_BC     16448    // float[512*8]  router per-block expert counts
#define WS_GP     33024    // float[8]   reduced by spr_finish block 0
#define WS_GC     33056    // float[8]
#define WS_SIMP   65536    // float[KS][65536], fully written by spr_gemm

// ---------------------------------------------------------------------------
// Router: 512 blocks x 512 threads (8 waves), W staged once in 64KB LDS.
// Each wave computes 4 tokens, it-loop OUTER: each W fragment is read from
// LDS once and FMA'd into 4 tokens' f32 accumulators. f32 logits (error
// ~1e-8 vs top-2 gap ~0.1 -> top-k safe). Log-fold shuffle reduction.
// NO global atomics: per-block partial P/C written with plain stores.
// ---------------------------------------------------------------------------
__global__ __launch_bounds__(512, 4) void router_k(
    const float* __restrict__ x, const float* __restrict__ W,
    float* __restrict__ out, float* __restrict__ blockP, float* __restrict__ blockC)
{
    __shared__ float4 Wl[NE * 512];   // 64 KB
    __shared__ float Pl[NE], Cl[NE];
    const int tid = threadIdx.x;
    {
        const float4* W4 = (const float4*)W;
#pragma unroll
        for (int i = 0; i < 8; ++i) Wl[tid + i * 512] = W4[tid + i * 512];
    }
    if (tid < NE) { Pl[tid] = 0.f; Cl[tid] = 0.f; }
    __syncthreads();

    const int wave = tid >> 6, lane = tid & 63;
    const int keep5 = (lane >> 5) & 1, keep4 = (lane >> 4) & 1, keep3 = (lane >> 3) & 1;
    const int emine = keep3 + 2 * keep4 + 4 * keep5;  // expert owned after folding
    const int t0 = blockIdx.x * 32 + wave * 4;        // this wave's 4 tokens

    const float4* xp = (const float4*)(x + (size_t)t0 * D_MODEL);  // token t at +t*512

    float acc[4][NE] = {};
#pragma unroll 2
    for (int it = 0; it < 8; ++it) {
        float4 xv[4];
#pragma unroll
        for (int t = 0; t < 4; ++t) xv[t] = xp[t * 512 + it * 64 + lane];
#pragma unroll
        for (int e = 0; e < NE; ++e) {
            const float4 wv = Wl[e * 512 + it * 64 + lane];
#pragma unroll
            for (int t = 0; t < 4; ++t)
                acc[t][e] += xv[t].x * wv.x + xv[t].y * wv.y +
                             xv[t].z * wv.z + xv[t].w * wv.w;
        }
    }

    float localP = 0.f, localC = 0.f;
#pragma unroll
    for (int tt = 0; tt < 4; ++tt) {            // FULLY unrolled (no dyn reg idx)
        const int t = t0 + tt;
        float a[NE];
#pragma unroll
        for (int e = 0; e < NE; ++e) a[e] = acc[tt][e];

        // ---- log-fold reduce: experts fold into 8-lane groups ----
#pragma unroll
        for (int j = 0; j < 4; ++j) {           // xor 32
            float keep = keep5 ? a[j + 4] : a[j];
            float send = keep5 ? a[j] : a[j + 4];
            a[j] = keep + __shfl_xor(send, 32, 64);
        }
#pragma unroll
        for (int j = 0; j < 2; ++j) {           // xor 16
            float keep = keep4 ? a[j + 2] : a[j];
            float send = keep4 ? a[j] : a[j + 2];
            a[j] = keep + __shfl_xor(send, 16, 64);
        }
        {                                        // xor 8
            float keep = keep3 ? a[1] : a[0];
            float send = keep3 ? a[0] : a[1];
            a[0] = keep + __shfl_xor(send, 8, 64);
        }
        float L = a[0];
        L += __shfl_xor(L, 4, 64);
        L += __shfl_xor(L, 2, 64);
        L += __shfl_xor(L, 1, 64);
        // L = logit[emine]; identical across the 8 lanes of each group.

        // top-1 across groups (lowest index wins ties = jax.lax.top_k)
        float v1 = L; int i1 = emine;
#pragma unroll
        for (int off = 8; off <= 32; off <<= 1) {
            float ov = __shfl_xor(v1, off, 64);
            int oi = __shfl_xor(i1, off, 64);
            if (ov > v1 || (ov == v1 && oi < i1)) { v1 = ov; i1 = oi; }
        }
        // top-2
        float v2 = (emine == i1) ? -3.4e38f : L;
        int i2 = (emine == i1) ? NE : emine;
#pragma unroll
        for (int off = 8; off <= 32; off <<= 1) {
            float ov = __shfl_xor(v2, off, 64);
            int oi = __shfl_xor(i2, off, 64);
            if (ov > v2 || (ov == v2 && oi < i2)) { v2 = ov; i2 = oi; }
        }
        // softmax
        float p = __expf(L - v1);
        float s = p;
#pragma unroll
        for (int off = 8; off <= 32; off <<= 1) s += __shfl_xor(s, off, 64);
        const float pr = p / s;

        localP += pr;
        localC += ((emine == i1) ? 1.f : 0.f) + ((emine == i2) ? 1.f : 0.f);

        if ((lane & 7) == 0) out[(size_t)t * NE + emine] = pr;
        if (lane == 0) {
            out[OUT_IDX + t * 2]     = (float)i1;
            out[OUT_IDX + t * 2 + 1] = (float)i2;
            const float e2 = __expf(v2 - v1);   // pr2/pr1
            out[OUT_TOPP + t * 2]     = 1.0f / (1.0f + e2);
            out[OUT_TOPP + t * 2 + 1] = e2 / (1.0f + e2);
        }
    }
    // per-wave -> per-block partials (LDS atomics, 64 per block), plain-store out
    if ((lane & 7) == 0) {
        atomicAdd(&Pl[emine], localP);
        atomicAdd(&Cl[emine], localC);
    }
    __syncthreads();
    if (tid < NE) {
        blockP[blockIdx.x * NE + tid] = Pl[tid];
        blockC[blockIdx.x * NE + tid] = Cl[tid];
    }
}

// ---------------------------------------------------------------------------
// SPR raw-dot GEMM, grid (4,4,KS), 256 thr, 64x64 tile, 4x4 reg blocking.
// Each bk writes its own partial buffer (no atomics). nkc = 32/KS.
// ---------------------------------------------------------------------------
__global__ __launch_bounds__(256) void spr_gemm(
    const float* __restrict__ x, const int* __restrict__ spr_idx,
    float* __restrict__ simP, int nkc)
{
    __shared__ float A[64][65];
    __shared__ float B[64][65];
    __shared__ int ra[64], rb[64];
    const int bi = blockIdx.x, bj = blockIdx.y, bk = blockIdx.z;
    const int tid = threadIdx.x;
    if (tid < 64) ra[tid] = spr_idx[bi * 64 + tid];
    else if (tid < 128) rb[tid - 64] = spr_idx[bj * 64 + (tid - 64)];
    __syncthreads();

    const int tx = tid & 15, ty = tid >> 4;
    float acc[4][4] = {};

    for (int kc = 0; kc < nkc; ++kc) {
        const int k0 = (bk * nkc + kc) * 64;
#pragma unroll
        for (int l = 0; l < 4; ++l) {
            const int lin = l * 256 + tid;
            const int r = lin >> 4, c4 = lin & 15;
            float4 v = *(const float4*)(x + (size_t)ra[r] * D_MODEL + k0 + c4 * 4);
            A[r][c4 * 4] = v.x; A[r][c4 * 4 + 1] = v.y; A[r][c4 * 4 + 2] = v.z; A[r][c4 * 4 + 3] = v.w;
            float4 w = *(const float4*)(x + (size_t)rb[r] * D_MODEL + k0 + c4 * 4);
            B[r][c4 * 4] = w.x; B[r][c4 * 4 + 1] = w.y; B[r][c4 * 4 + 2] = w.z; B[r][c4 * 4 + 3] = w.w;
        }
        __syncthreads();
#pragma unroll 4
        for (int k = 0; k < 64; ++k) {
            float a[4], b[4];
#pragma unroll
            for (int u = 0; u < 4; ++u) { a[u] = A[ty * 4 + u][k]; b[u] = B[tx * 4 + u][k]; }
#pragma unroll
            for (int u = 0; u < 4; ++u)
#pragma unroll
                for (int v = 0; v < 4; ++v) acc[u][v] += a[u] * b[v];
        }
        __syncthreads();
    }
    float* dst = simP + (size_t)bk * 65536;
#pragma unroll
    for (int u = 0; u < 4; ++u)
#pragma unroll
        for (int v = 0; v < 4; ++v)
            dst[(bi * 64 + ty * 4 + u) * 256 + (bj * 64 + tx * 4 + v)] = acc[u][v];
}

// ---------------------------------------------------------------------------
// SPR loss + finalize. 256 blocks (row i) x 256 threads (col j).
// Block 0 additionally reduces the router's per-block P/C partials -> gP/gC.
// Last block (counter) computes the aux loss.
// ---------------------------------------------------------------------------
__global__ __launch_bounds__(256) void spr_finish(
    const float* __restrict__ simP, const int* __restrict__ spr_idx,
    const float* __restrict__ out_probs, const float* __restrict__ blockP,
    const float* __restrict__ blockC, float* __restrict__ gP, float* __restrict__ gC,
    double* __restrict__ spr_sum, unsigned* __restrict__ counter,
    float* __restrict__ out, int ks)
{
    const int i = blockIdx.x, j = threadIdx.x;
    __shared__ float rni[NE];
    __shared__ double red[4];

    // ---- block 0: reduce router partials (512 blocks x 8 experts) ----
    if (i == 0) {
        __shared__ float rP[32][NE], rC[32][NE];
        const int e = j & 7, c = j >> 3;           // 32 chunks x 16 blocks
        float sp = 0.f, sc = 0.f;
#pragma unroll
        for (int b = 0; b < 16; ++b) {
            sp += blockP[(c * 16 + b) * NE + e];
            sc += blockC[(c * 16 + b) * NE + e];
        }
        rP[c][e] = sp; rC[c][e] = sc;
        __syncthreads();
        if (j < NE) {
            float P = 0.f, C = 0.f;
            for (int cc = 0; cc < 32; ++cc) { P += rP[cc][j]; C += rC[cc][j]; }
            gP[j] = P; gC[j] = C;
        }
        __syncthreads();
    }

    float raw = 0.f, dj = 0.f;
    for (int s = 0; s < ks; ++s) raw += simP[(size_t)s * 65536 + i * 256 + j];
    for (int s = 0; s < ks; ++s) dj  += simP[(size_t)s * 65536 + j * 257];

    const int rowj = spr_idx[j];
    const float4* pp = (const float4*)(out_probs + (size_t)rowj * NE);
    float4 pv0 = pp[0], pv1 = pp[1];
    float rs = pv0.x * pv0.x + pv0.y * pv0.y + pv0.z * pv0.z + pv0.w * pv0.w +
               pv1.x * pv1.x + pv1.y * pv1.y + pv1.z * pv1.z + pv1.w * pv1.w;
    const float rinv = 1.0f / fmaxf(sqrtf(rs), 1e-12f);
    float rnj[NE] = { pv0.x * rinv, pv0.y * rinv, pv0.z * rinv, pv0.w * rinv,
                      pv1.x * rinv, pv1.y * rinv, pv1.z * rinv, pv1.w * rinv };
    if (j == i) {
#pragma unroll
        for (int e = 0; e < NE; ++e) rni[e] = rnj[e];
        red[3] = (double)dj;
    }
    __syncthreads();
    const float di = (float)red[3];
    float rsim = 0.f;
#pragma unroll
    for (int e = 0; e < NE; ++e) rsim += rni[e] * rnj[e];
    const float ni = fmaxf(sqrtf(di), 1e-12f), nj = fmaxf(sqrtf(dj), 1e-12f);
    const float isim = raw / (ni * nj);
    const double d = (double)rsim - (double)isim;
    double sq = d * d;
#pragma unroll
    for (int off = 32; off; off >>= 1) sq += __shfl_xor(sq, off, 64);
    __syncthreads();
    const int wave = j >> 6, lane = j & 63;
    if (lane == 0) red[wave] = sq;
    __syncthreads();
    if (j == 0) {
        atomicAdd(spr_sum, red[0] + red[1] + red[2] + red[3]);
        __threadfence();
        const unsigned old = atomicAdd(counter, 1u);
        if (old == 255u) {
            const double spr = atomicAdd(spr_sum, 0.0) / 65536.0;  // coherent read
            double lb = 0.0, dpsl = 0.0;
            for (int e = 0; e < NE; ++e) {
                const double Pi = (double)atomicAdd(&gP[e], 0.f) / (double)TOKENS;
                const double fi = (double)atomicAdd(&gC[e], 0.f) / (double)(TOKENS * 2);
                lb += fi * Pi;
                dpsl += 0.125 * (log(0.125) - log(Pi));
            }
            lb *= 8.0;
            out[OUT_AUX] = (float)(0.01 * (lb + dpsl + 0.1 * spr));
        }
    }
}

extern "C" void kernel_launch(void* const* d_in, const int* in_sizes, int n_in,
                              void* d_out, int out_size, void* d_ws, size_t ws_size,
                              hipStream_t stream)
{
    const float* x = (const float*)d_in[0];
    const float* W = (const float*)d_in[1];
    const int* spr_idx = (const int*)d_in[2];
    float* out = (float*)d_out;
    char* ws = (char*)d_ws;

    double*   spr_sum = (double*)(ws + WS_SPR);
    unsigned* counter = (unsigned*)(ws + WS_CNT);
    float*    blockP  = (float*)(ws + WS_BP);
    float*    blockC  = (float*)(ws + WS_BC);
    float*    gP      = (float*)(ws + WS_GP);
    float*    gC      = (float*)(ws + WS_GC);
    float*    simP    = (float*)(ws + WS_SIMP);

    // pick largest K-split whose partial buffers fit the workspace
    int ks = 8;
    if (ws_size >= (size_t)WS_SIMP + 32u * 65536u * 4u) ks = 32;
    else if (ws_size >= (size_t)WS_SIMP + 16u * 65536u * 4u) ks = 16;
    const int nkc = 32 / ks;

    hipMemsetAsync(ws, 0, 16, stream);   // spr_sum + counter only

    router_k<<<RBLK, 512, 0, stream>>>(x, W, out, blockP, blockC);
    spr_gemm<<<dim3(4, 4, ks), 256, 0, stream>>>(x, spr_idx, simP, nkc);
    spr_finish<<<256, 256, 0, stream>>>(simP, spr_idx, out, blockP, blockC,
                                        gP, gC, spr_sum, counter, out, ks);
}